// Round 6
// baseline (3448.539 us; speedup 1.0000x reference)
//
#include <hip/hip_runtime.h>
#include <cstdint>
#include <cstddef>

#define N_POS 196

typedef __attribute__((ext_vector_type(4))) float f32x4;

// async global->LDS DMA, 16B per lane; lds dest must be wave-uniform base (+lane*16)
__device__ __forceinline__ void async_copy16(const float* g, float* l) {
    __builtin_amdgcn_global_load_lds(
        (const __attribute__((address_space(1))) uint32_t*)g,
        (__attribute__((address_space(3))) uint32_t*)l,
        16, 0, 0);
}

// ---------------- W transpose: A[R][C] -> At[C][R] ----------------
__global__ __launch_bounds__(256) void transpose_kernel(
    const float* __restrict__ A, float* __restrict__ At, int R, int C)
{
    __shared__ float tile[32][33];
    const int c0 = blockIdx.x * 32, r0 = blockIdx.y * 32;
    const int tx = threadIdx.x & 31, ty = threadIdx.x >> 5;   // ty in [0,8)
    #pragma unroll
    for (int dy = 0; dy < 32; dy += 8) {
        int r = r0 + ty + dy, c = c0 + tx;
        if (r < R && c < C) tile[ty + dy][tx] = A[(size_t)r * C + c];
    }
    __syncthreads();
    #pragma unroll
    for (int dy = 0; dy < 32; dy += 8) {
        int c = c0 + ty + dy, r = r0 + tx;
        if (c < C && r < R) At[(size_t)c * R + r] = tile[tx][ty + dy];
    }
}

// ---------------- 1x1 conv (channel matmul) + folded BatchNorm ----------------
// X: (ntb, CIN, 196)  Wt: (CIN, Cout) TRANSPOSED  Y: (ntb, Cout, 196)
// Block: 512 thr, one tb, 64 outputs (8 per wave). Thread owns 4 consecutive
// positions (quad q4) x 8 outputs. X staged in LDS (16-k chunks, double-buffered
// DMA); W read via wave-uniform scalar loads (s_load) from Wt — no LDS traffic.
// Packed f32x4 math: same per-element IEEE ops, same ascending-k order as np.
// USE_FMA=false: mul-then-add (continuous inputs, bitwise == np.einsum).
// USE_FMA=true: fma — bitwise identical for binary {0,1} inputs. ACCUM: Y += r.
template<int CIN, bool USE_FMA, bool ACCUM>
__global__ __launch_bounds__(512) void convbn_kernel(
    const float* __restrict__ X, const float* __restrict__ Wt,
    const float* __restrict__ Bi, const float* __restrict__ Ga,
    const float* __restrict__ Be, const float* __restrict__ Mu,
    const float* __restrict__ Va, float* __restrict__ Y, int Cout,
    int nb, int b0, int xlocal, int ylocal)
{
#pragma clang fp contract(off)
    constexpr int NCH = CIN / 16;
    __shared__ f32x4 XsV[2 * 784];            // 2 x [16][196] floats, 25088 B
    float* Xs = (float*)XsV;
    const int tid = threadIdx.x;
    const int l   = blockIdx.x;
    const int t   = l / nb;
    const int bl  = l - t * nb;
    const int tbg = t * 32 + b0 + bl;
    const int xtb = xlocal ? l : tbg;
    const int ytb = ylocal ? l : tbg;
    const int o0  = blockIdx.y * 64;
    const int lane = tid & 63;
    const int ob  = __builtin_amdgcn_readfirstlane((tid >> 6) * 8); // wave out base
    const int q4  = (lane < 49) ? lane : 48;   // position quad; dup for dead lanes
    const bool alive = (lane < 49);
    const float* Xtb = X + (size_t)xtb * CIN * N_POS;

    f32x4 acc[8];
    #pragma unroll
    for (int i = 0; i < 8; ++i) acc[i] = (f32x4)0.f;

    auto stage = [&](int buf, int kc) {
        int i = tid;
        async_copy16(Xtb + (size_t)(kc + i / 49) * N_POS + (i % 49) * 4,
                     &Xs[buf * 3136 + (i & ~63) * 4]);
        if (tid < 272) {
            i = tid + 512;
            async_copy16(Xtb + (size_t)(kc + i / 49) * N_POS + (i % 49) * 4,
                         &Xs[buf * 3136 + (i & ~63) * 4]);
        }
    };

    stage(0, 0);
    __syncthreads();                 // drains prologue DMA
    int buf = 0;
    for (int ch = 0; ch < NCH; ++ch) {
        if (ch + 1 < NCH) stage(buf ^ 1, (ch + 1) * 16);
        const float* Xb = Xs + buf * 3136;
        const float* Wk = Wt + (size_t)(ch * 16) * Cout + o0 + ob;   // uniform
        #pragma unroll 8
        for (int kk = 0; kk < 16; ++kk) {
            f32x4 xq = *(const f32x4*)(Xb + kk * 196 + q4 * 4);      // ds_read_b128
            const float* wr = Wk + (size_t)kk * Cout;                // uniform -> s_load
            float w8[8];
            #pragma unroll
            for (int i = 0; i < 8; ++i) w8[i] = wr[i];
            #pragma unroll
            for (int i = 0; i < 8; ++i) {
                f32x4 wd = { w8[i], w8[i], w8[i], w8[i] };
                if (USE_FMA) acc[i] = __builtin_elementwise_fma(wd, xq, acc[i]);
                else         acc[i] = acc[i] + wd * xq;   // pk_mul + pk_add, no contract
            }
        }
        __syncthreads();             // next chunk DMA complete; buf safe to reuse
        buf ^= 1;
    }

    #pragma unroll
    for (int i = 0; i < 8; ++i) {
        int o = o0 + ob + i;
        // match reference op-for-op: inv = g*rsqrt(var+eps); y = conv (+ bias);
        // r = y*inv + (beta - m*inv)
        float sc = __fmul_rn(Ga[o], 1.0f / sqrtf(__fadd_rn(Va[o], 1e-5f)));
        float sh = __fsub_rn(Be[o], __fmul_rn(Mu[o], sc));
        if (!alive) continue;
        float* yp = Y + ((size_t)ytb * Cout + o) * N_POS + q4 * 4;
        float r0_ = acc[i].x, r1_ = acc[i].y, r2_ = acc[i].z, r3_ = acc[i].w;
        if (Bi) {
            float b = Bi[o];
            r0_ = __fadd_rn(r0_, b); r1_ = __fadd_rn(r1_, b);
            r2_ = __fadd_rn(r2_, b); r3_ = __fadd_rn(r3_, b);
        }
        float4 r;
        r.x = __fadd_rn(__fmul_rn(r0_, sc), sh);
        r.y = __fadd_rn(__fmul_rn(r1_, sc), sh);
        r.z = __fadd_rn(__fmul_rn(r2_, sc), sh);
        r.w = __fadd_rn(__fmul_rn(r3_, sc), sh);
        if (ACCUM) {
            float4 y = *(const float4*)yp;
            r.x = __fadd_rn(y.x, r.x); r.y = __fadd_rn(y.y, r.y);
            r.z = __fadd_rn(y.z, r.z); r.w = __fadd_rn(y.w, r.w);
        }
        *(float4*)yp = r;
    }
}

// ---------------- multi-step LIF (in place, scan over T=4) ----------------
__global__ __launch_bounds__(256) void lif_kernel(float* __restrict__ Y, int plane4, float thr)
{
    int idx = blockIdx.x * 256 + threadIdx.x;
    if (idx >= plane4) return;
    float4* Yp = (float4*)Y;
    float v0 = 0.f, v1 = 0.f, v2 = 0.f, v3 = 0.f;
    #pragma unroll
    for (int t = 0; t < 4; ++t) {
        float4 xv = Yp[(size_t)t * plane4 + idx];
        v0 = __fadd_rn(v0, __fmul_rn(__fsub_rn(xv.x, v0), 0.5f));
        v1 = __fadd_rn(v1, __fmul_rn(__fsub_rn(xv.y, v1), 0.5f));
        v2 = __fadd_rn(v2, __fmul_rn(__fsub_rn(xv.z, v2), 0.5f));
        v3 = __fadd_rn(v3, __fmul_rn(__fsub_rn(xv.w, v3), 0.5f));
        float s0 = (__fsub_rn(v0, thr) >= 0.f) ? 1.f : 0.f;
        float s1 = (__fsub_rn(v1, thr) >= 0.f) ? 1.f : 0.f;
        float s2 = (__fsub_rn(v2, thr) >= 0.f) ? 1.f : 0.f;
        float s3 = (__fsub_rn(v3, thr) >= 0.f) ? 1.f : 0.f;
        v0 = __fmul_rn(v0, 1.f - s0); v1 = __fmul_rn(v1, 1.f - s1);
        v2 = __fmul_rn(v2, 1.f - s2); v3 = __fmul_rn(v3, 1.f - s3);
        xv.x = s0; xv.y = s1; xv.z = s2; xv.w = s3;
        Yp[(size_t)t * plane4 + idx] = xv;
    }
}

// ---------------- LIF scan + accumulate spikes into global output ----------------
__global__ __launch_bounds__(256) void lif_add_kernel(
    const float* __restrict__ Yin, float* __restrict__ Out, int b0)
{
    const int PL4 = 8 * 384 * 49;
    const int B4  = 384 * 49;
    int idx = blockIdx.x * 256 + threadIdx.x;
    if (idx >= PL4) return;
    int bl = idx / B4, r = idx - bl * B4;
    const float4* Yp = (const float4*)Yin;
    float v0 = 0.f, v1 = 0.f, v2 = 0.f, v3 = 0.f;
    #pragma unroll
    for (int t = 0; t < 4; ++t) {
        float4 xv = Yp[(size_t)t * PL4 + idx];
        v0 = __fadd_rn(v0, __fmul_rn(__fsub_rn(xv.x, v0), 0.5f));
        v1 = __fadd_rn(v1, __fmul_rn(__fsub_rn(xv.y, v1), 0.5f));
        v2 = __fadd_rn(v2, __fmul_rn(__fsub_rn(xv.z, v2), 0.5f));
        v3 = __fadd_rn(v3, __fmul_rn(__fsub_rn(xv.w, v3), 0.5f));
        float s0 = (__fsub_rn(v0, 1.0f) >= 0.f) ? 1.f : 0.f;
        float s1 = (__fsub_rn(v1, 1.0f) >= 0.f) ? 1.f : 0.f;
        float s2 = (__fsub_rn(v2, 1.0f) >= 0.f) ? 1.f : 0.f;
        float s3 = (__fsub_rn(v3, 1.0f) >= 0.f) ? 1.f : 0.f;
        v0 = __fmul_rn(v0, 1.f - s0); v1 = __fmul_rn(v1, 1.f - s1);
        v2 = __fmul_rn(v2, 1.f - s2); v3 = __fmul_rn(v3, 1.f - s3);
        float4* op = (float4*)Out + ((size_t)(t * 32 + b0 + bl) * B4 + r);
        float4 o = *op;
        o.x = __fadd_rn(o.x, s0); o.y = __fadd_rn(o.y, s1);
        o.z = __fadd_rn(o.z, s2); o.w = __fadd_rn(o.w, s3);
        *op = o;
    }
}

// ---------------- pack 32 head-channels of binary spikes into uint32 ----------------
__global__ __launch_bounds__(256) void pack_kernel(const float* __restrict__ S,
                                                   uint32_t* __restrict__ Bits)
{
    int idx = blockIdx.x * 256 + threadIdx.x;
    if (idx >= 4 * 32 * 12 * 196) return;
    int n = idx % 196;
    int rest = idx / 196;
    int h = rest % 12;
    int tb = rest / 12;
    const float* sp = S + ((size_t)tb * 384 + h * 32) * 196 + n;
    uint32_t bits = 0;
    #pragma unroll
    for (int d = 0; d < 32; ++d)
        bits |= (sp[(size_t)d * 196] > 0.5f) ? (1u << d) : 0u;
    Bits[idx] = bits;
}

// ---------------- attention: attn = popc(q&k), policy mask, o = attn*v*0.25 ----------------
__global__ __launch_bounds__(256) void attn_kernel(
    const uint32_t* __restrict__ Qb, const uint32_t* __restrict__ Kb,
    const float* __restrict__ V, const float* __restrict__ P, float* __restrict__ O)
{
    __shared__ uint32_t Qbs[196], Kbs[196];
    __shared__ float Ps[196];
    __shared__ float Vs[32][204];
    __shared__ float Ss[32][204];
    __shared__ float Os[32][36];
    const int tid = threadIdx.x;
    const int bid = blockIdx.x;
    const int tb = bid / 12, h = bid - tb * 12;
    const size_t vbase = ((size_t)tb * 384 + h * 32) * 196;
    const size_t qbase = ((size_t)tb * 12 + h) * 196;
    for (int i = tid; i < 196; i += 256) {
        Qbs[i] = Qb[qbase + i];
        Kbs[i] = Kb[qbase + i];
        Ps[i]  = P[(size_t)tb * 196 + i];
    }
    for (int i = tid; i < 32 * 49; i += 256) {
        int d = i / 49, m4 = i - d * 49;
        *(float4*)&Vs[d][m4 * 4] = *(const float4*)(V + vbase + (size_t)d * 196 + m4 * 4);
    }
    __syncthreads();
    for (int n0 = 0; n0 < 196; n0 += 32) {
        const int rows = min(32, 196 - n0);
        for (int idx = tid; idx < rows * 196; idx += 256) {
            int ns = idx / 196, m = idx - ns * 196;
            int n = n0 + ns;
            float s = (float)__popc(Qbs[n] & Kbs[m]);
            float p = Ps[m];
            float e = (m == n) ? 1.f : 0.f;
            Ss[ns][m] = s * (p + (1.f - p) * e);
        }
        __syncthreads();
        {
            const int tn = tid & 15, td = tid >> 4;
            float a00 = 0, a01 = 0, a10 = 0, a11 = 0;
            #pragma unroll 7
            for (int m4 = 0; m4 < 49; ++m4) {
                float4 s0 = *(const float4*)&Ss[tn][m4 * 4];
                float4 s1 = *(const float4*)&Ss[tn + 16][m4 * 4];
                float4 u0 = *(const float4*)&Vs[td][m4 * 4];
                float4 u1 = *(const float4*)&Vs[td + 16][m4 * 4];
                a00 += s0.x * u0.x + s0.y * u0.y + s0.z * u0.z + s0.w * u0.w;
                a01 += s0.x * u1.x + s0.y * u1.y + s0.z * u1.z + s0.w * u1.w;
                a10 += s1.x * u0.x + s1.y * u0.y + s1.z * u0.z + s1.w * u0.w;
                a11 += s1.x * u1.x + s1.y * u1.y + s1.z * u1.z + s1.w * u1.w;
            }
            Os[td     ][tn     ] = a00 * 0.25f;
            Os[td + 16][tn     ] = a01 * 0.25f;
            Os[td     ][tn + 16] = a10 * 0.25f;
            Os[td + 16][tn + 16] = a11 * 0.25f;
        }
        __syncthreads();
        {
            const int d = tid >> 3, c4 = tid & 7;
            if (c4 * 4 < rows)
                *(float4*)(O + vbase + (size_t)d * 196 + n0 + c4 * 4) =
                    *(const float4*)&Os[d][c4 * 4];
        }
        __syncthreads();
    }
}

// ---------------- elementwise residual add: Out = A + B ----------------
__global__ __launch_bounds__(256) void add_kernel(const float* __restrict__ A,
    const float* __restrict__ B, float* __restrict__ Out, int n4)
{
    int idx = blockIdx.x * 256 + threadIdx.x;
    if (idx >= n4) return;
    float4 a = ((const float4*)A)[idx];
    float4 b = ((const float4*)B)[idx];
    float4 o;
    o.x = __fadd_rn(a.x, b.x); o.y = __fadd_rn(a.y, b.y);
    o.z = __fadd_rn(a.z, b.z); o.w = __fadd_rn(a.w, b.w);
    ((float4*)Out)[idx] = o;
}

extern "C" void kernel_launch(void* const* d_in, const int* in_sizes, int n_in,
                              void* d_out, int out_size, void* d_ws, size_t ws_size,
                              hipStream_t stream) {
    const float* x   = (const float*)d_in[0];
    const float* pol = (const float*)d_in[1];
    const float* wq = (const float*)d_in[2];
    const float* qg = (const float*)d_in[3];
    const float* qb = (const float*)d_in[4];
    const float* qm = (const float*)d_in[5];
    const float* qv = (const float*)d_in[6];
    const float* wk = (const float*)d_in[7];
    const float* kg = (const float*)d_in[8];
    const float* kb = (const float*)d_in[9];
    const float* km = (const float*)d_in[10];
    const float* kvv= (const float*)d_in[11];
    const float* wv = (const float*)d_in[12];
    const float* vg = (const float*)d_in[13];
    const float* vb = (const float*)d_in[14];
    const float* vm = (const float*)d_in[15];
    const float* vvv= (const float*)d_in[16];
    const float* wp = (const float*)d_in[17];
    const float* bp = (const float*)d_in[18];
    const float* pg = (const float*)d_in[19];
    const float* pb = (const float*)d_in[20];
    const float* pm = (const float*)d_in[21];
    const float* pv = (const float*)d_in[22];
    const float* w1 = (const float*)d_in[23];
    const float* b1 = (const float*)d_in[24];
    const float* g1 = (const float*)d_in[25];
    const float* be1= (const float*)d_in[26];
    const float* m1 = (const float*)d_in[27];
    const float* v1 = (const float*)d_in[28];
    const float* w2 = (const float*)d_in[29];
    const float* b2 = (const float*)d_in[30];
    const float* g2 = (const float*)d_in[31];
    const float* be2= (const float*)d_in[32];
    const float* m2 = (const float*)d_in[33];
    const float* v2 = (const float*)d_in[34];

    // workspace (floats), total 57.7 MiB:
    //   bufA 9,633,792 | bufD 2,408,448 | bits 602,112 u32 | Wt 1,769,472
    float* bufA = (float*)d_ws;
    float* bufD = bufA + 9633792;
    uint32_t* Qbits = (uint32_t*)(bufD + 2408448);
    uint32_t* Kbits = Qbits + 301056;
    float* wqT = (float*)(Kbits + 301056);
    float* wkT = wqT + 147456;
    float* wvT = wkT + 147456;
    float* wpT = wvT + 147456;
    float* w1T = wpT + 147456;
    float* w2T = w1T + 589824;
    float* out = (float*)d_out;

    // transpose all weights to Wt[k][o]
    transpose_kernel<<<dim3(12, 12), 256, 0, stream>>>(wq, wqT, 384, 384);
    transpose_kernel<<<dim3(12, 12), 256, 0, stream>>>(wk, wkT, 384, 384);
    transpose_kernel<<<dim3(12, 12), 256, 0, stream>>>(wv, wvT, 384, 384);
    transpose_kernel<<<dim3(12, 12), 256, 0, stream>>>(wp, wpT, 384, 384);
    transpose_kernel<<<dim3(12, 48), 256, 0, stream>>>(w1, w1T, 1536, 384);
    transpose_kernel<<<dim3(48, 12), 256, 0, stream>>>(w2, w2T, 384, 1536);

    // q branch: conv+bn, LIF, pack bits; bufA reused for k, then v
    convbn_kernel<384, false, false><<<dim3(128, 6), 512, 0, stream>>>(x, wqT, nullptr, qg, qb, qm, qv, bufA, 384, 32, 0, 0, 0);
    lif_kernel<<<2352, 256, 0, stream>>>(bufA, 602112, 1.0f);
    pack_kernel<<<1176, 256, 0, stream>>>(bufA, Qbits);
    convbn_kernel<384, false, false><<<dim3(128, 6), 512, 0, stream>>>(x, wkT, nullptr, kg, kb, km, kvv, bufA, 384, 32, 0, 0, 0);
    lif_kernel<<<2352, 256, 0, stream>>>(bufA, 602112, 1.0f);
    pack_kernel<<<1176, 256, 0, stream>>>(bufA, Kbits);
    convbn_kernel<384, false, false><<<dim3(128, 6), 512, 0, stream>>>(x, wvT, nullptr, vg, vb, vm, vvv, bufA, 384, 32, 0, 0, 0);
    lif_kernel<<<2352, 256, 0, stream>>>(bufA, 602112, 1.0f);

    // attention (exact popcount) -> d_out, then attn LIF (thr=0.5) in place
    attn_kernel<<<1536, 256, 0, stream>>>(Qbits, Kbits, bufA, pol, out);
    lif_kernel<<<2352, 256, 0, stream>>>(out, 602112, 0.5f);

    // projection conv+bn+LIF (binary input -> fma exact); residual 1: out = x + proj
    convbn_kernel<384, true, false><<<dim3(128, 6), 512, 0, stream>>>(out, wpT, bp, pg, pb, pm, pv, bufA, 384, 32, 0, 0, 0);
    lif_kernel<<<2352, 256, 0, stream>>>(bufA, 602112, 1.0f);
    add_kernel<<<9408, 256, 0, stream>>>(x, bufA, out, 2408448);   // out = x1

    // MLP chunked over b in groups of 8 (t recurrence preserved):
    // fc1 -> bufA (chunk-local); LIF; fc2 -> bufD; lif_add spikes into out.
    for (int c = 0; c < 4; ++c) {
        convbn_kernel<384, false, false><<<dim3(32, 24), 512, 0, stream>>>(out, w1T, b1, g1, be1, m1, v1, bufA, 1536, 8, c * 8, 0, 1);
        lif_kernel<<<2352, 256, 0, stream>>>(bufA, 602112, 1.0f);
        convbn_kernel<1536, true, false><<<dim3(32, 6), 512, 0, stream>>>(bufA, w2T, b2, g2, be2, m2, v2, bufD, 384, 8, c * 8, 1, 1);
        lif_add_kernel<<<588, 256, 0, stream>>>(bufD, out, c * 8);
    }
}

// Round 7
// 2654.103 us; speedup vs baseline: 1.2993x; 1.2993x over previous
//
#include <hip/hip_runtime.h>
#include <cstdint>
#include <cstddef>

#define N_POS 196

typedef __attribute__((ext_vector_type(2))) float f32x2;

// async global->LDS DMA, 16B per lane; lds dest must be wave-uniform base (+lane*16)
__device__ __forceinline__ void async_copy16(const float* g, float* l) {
    __builtin_amdgcn_global_load_lds(
        (const __attribute__((address_space(1))) uint32_t*)g,
        (__attribute__((address_space(3))) uint32_t*)l,
        16, 0, 0);
}

// ---------------- 1x1 conv (channel matmul) + folded BatchNorm ----------------
// X: (ntb, CIN, 196)  W: (Cout, CIN) row-major  Y: (ntb, Cout, 196)
// Block: 512 thr, one tb, 64 outputs (8/wave, wave-uniform). Thread: 8 outs x 4 pos
// (n0, n0+64, n0+128, col3). X DMA-staged in LDS 16-k chunks (double-buffered);
// W scatter-staged to LDS [k][o]; per-kk W read = 2x b128 wave-broadcast.
// Math: packed f32x2 (v_pk_*), per-element IEEE == scalar, ascending-k sequential
// per accumulator — bitwise-matches np.einsum (proven absmax 0.0 r4/r5/r6).
// USE_FMA=false: pk_mul+pk_add (continuous inputs). USE_FMA=true: pk_fma —
// bitwise identical for binary {0,1} inputs. ACCUM: Y += result.
template<int CIN, bool USE_FMA, bool ACCUM>
__global__ __launch_bounds__(512, 4) void convbn_kernel(
    const float* __restrict__ X, const float* __restrict__ W,
    const float* __restrict__ Bi, const float* __restrict__ Ga,
    const float* __restrict__ Be, const float* __restrict__ Mu,
    const float* __restrict__ Va, float* __restrict__ Y, int Cout,
    int nb, int b0, int xlocal, int ylocal)
{
#pragma clang fp contract(off)
    constexpr int NCH = CIN / 16;
    // Xs[2][16*196] then Ws[2][16*64]  (33280 B)
    __shared__ float lds[2 * 3136 + 2 * 1024];
    float* Xs = lds;
    float* Ws = lds + 6272;
    const int tid = threadIdx.x;
    const int l   = blockIdx.x;
    const int t   = l / nb;
    const int bl  = l - t * nb;
    const int tbg = t * 32 + b0 + bl;
    const int xtb = xlocal ? l : tbg;
    const int ytb = ylocal ? l : tbg;
    const int o0  = blockIdx.y * 64;
    const int n0  = tid & 63;
    const int obase = (tid >> 6) * 8;             // wave-uniform
    const int col3 = (n0 < 4) ? (n0 + 192) : 196; // n0>=4: dead in-bounds read
    const float* Xtb = X + (size_t)xtb * CIN * N_POS;
    const float* Wp  = W + (size_t)o0 * CIN;

    f32x2 acc01[8], acc23[8];
    #pragma unroll
    for (int i = 0; i < 8; ++i) { acc01[i] = (f32x2)0.f; acc23[i] = (f32x2)0.f; }

    // stage chunk kc..kc+15: W->VGPR first, X DMA (stays in flight), W ds_writes
    auto stage = [&](int buf, int kc) {
        const int oo = tid >> 3, k2 = (tid & 7) * 2;
        float2 wv2 = *(const float2*)(Wp + (size_t)oo * CIN + kc + k2);
        {
            int i = tid;
            async_copy16(Xtb + (size_t)(kc + i / 49) * N_POS + (i % 49) * 4,
                         &Xs[buf * 3136 + (i & ~63) * 4]);
        }
        if (tid < 272) {
            int i = tid + 512;
            async_copy16(Xtb + (size_t)(kc + i / 49) * N_POS + (i % 49) * 4,
                         &Xs[buf * 3136 + (i & ~63) * 4]);
        }
        Ws[buf * 1024 + k2 * 64 + oo]       = wv2.x;
        Ws[buf * 1024 + (k2 + 1) * 64 + oo] = wv2.y;
    };

    stage(0, 0);
    __syncthreads();                 // drains prologue DMA
    int buf = 0;
    for (int ch = 0; ch < NCH; ++ch) {
        if (ch + 1 < NCH) stage(buf ^ 1, (ch + 1) * 16);
        const float* Xb = Xs + buf * 3136;
        const float* Wb = Ws + buf * 1024;
        #pragma unroll
        for (int kk = 0; kk < 16; ++kk) {
            float4 wA = *(const float4*)(Wb + kk * 64 + obase);      // bcast b128
            float4 wB = *(const float4*)(Wb + kk * 64 + obase + 4);
            f32x2 x01 = { Xb[kk * 196 + n0],       Xb[kk * 196 + n0 + 64] };
            f32x2 x23 = { Xb[kk * 196 + n0 + 128], Xb[kk * 196 + col3] };
            float w8[8] = { wA.x, wA.y, wA.z, wA.w, wB.x, wB.y, wB.z, wB.w };
            #pragma unroll
            for (int i = 0; i < 8; ++i) {
                f32x2 wd = { w8[i], w8[i] };
                if (USE_FMA) {
                    acc01[i] = __builtin_elementwise_fma(wd, x01, acc01[i]);
                    acc23[i] = __builtin_elementwise_fma(wd, x23, acc23[i]);
                } else {
                    acc01[i] = acc01[i] + wd * x01;   // v_pk_mul + v_pk_add
                    acc23[i] = acc23[i] + wd * x23;
                }
            }
        }
        __syncthreads();             // next chunk DMA complete; buf reusable
        buf ^= 1;
    }

    #pragma unroll
    for (int i = 0; i < 8; ++i) {
        int o = o0 + obase + i;
        // reference op order: inv = g*rsqrt(var+eps); y = conv (+ bias);
        // r = y*inv + (beta - m*inv)
        float sc = __fmul_rn(Ga[o], 1.0f / sqrtf(__fadd_rn(Va[o], 1e-5f)));
        float sh = __fsub_rn(Be[o], __fmul_rn(Mu[o], sc));
        float* yp = Y + ((size_t)ytb * Cout + o) * N_POS;
        float a[4] = { acc01[i].x, acc01[i].y, acc23[i].x, acc23[i].y };
        #pragma unroll
        for (int j = 0; j < 4; ++j) {
            if (j == 3 && n0 >= 4) continue;
            float y = a[j];
            if (Bi) y = __fadd_rn(y, Bi[o]);
            float r = __fadd_rn(__fmul_rn(y, sc), sh);
            int n = n0 + j * 64;
            if (ACCUM) yp[n] = __fadd_rn(yp[n], r);
            else       yp[n] = r;
        }
    }
}

// ---------------- multi-step LIF (in place, scan over T=4) ----------------
__global__ __launch_bounds__(256) void lif_kernel(float* __restrict__ Y, int plane4, float thr)
{
    int idx = blockIdx.x * 256 + threadIdx.x;
    if (idx >= plane4) return;
    float4* Yp = (float4*)Y;
    float v0 = 0.f, v1 = 0.f, v2 = 0.f, v3 = 0.f;
    #pragma unroll
    for (int t = 0; t < 4; ++t) {
        float4 xv = Yp[(size_t)t * plane4 + idx];
        v0 = __fadd_rn(v0, __fmul_rn(__fsub_rn(xv.x, v0), 0.5f));
        v1 = __fadd_rn(v1, __fmul_rn(__fsub_rn(xv.y, v1), 0.5f));
        v2 = __fadd_rn(v2, __fmul_rn(__fsub_rn(xv.z, v2), 0.5f));
        v3 = __fadd_rn(v3, __fmul_rn(__fsub_rn(xv.w, v3), 0.5f));
        float s0 = (__fsub_rn(v0, thr) >= 0.f) ? 1.f : 0.f;
        float s1 = (__fsub_rn(v1, thr) >= 0.f) ? 1.f : 0.f;
        float s2 = (__fsub_rn(v2, thr) >= 0.f) ? 1.f : 0.f;
        float s3 = (__fsub_rn(v3, thr) >= 0.f) ? 1.f : 0.f;
        v0 = __fmul_rn(v0, 1.f - s0); v1 = __fmul_rn(v1, 1.f - s1);
        v2 = __fmul_rn(v2, 1.f - s2); v3 = __fmul_rn(v3, 1.f - s3);
        xv.x = s0; xv.y = s1; xv.z = s2; xv.w = s3;
        Yp[(size_t)t * plane4 + idx] = xv;
    }
}

// ---------------- LIF scan + accumulate spikes into global output ----------------
__global__ __launch_bounds__(256) void lif_add_kernel(
    const float* __restrict__ Yin, float* __restrict__ Out, int b0)
{
    const int PL4 = 8 * 384 * 49;
    const int B4  = 384 * 49;
    int idx = blockIdx.x * 256 + threadIdx.x;
    if (idx >= PL4) return;
    int bl = idx / B4, r = idx - bl * B4;
    const float4* Yp = (const float4*)Yin;
    float v0 = 0.f, v1 = 0.f, v2 = 0.f, v3 = 0.f;
    #pragma unroll
    for (int t = 0; t < 4; ++t) {
        float4 xv = Yp[(size_t)t * PL4 + idx];
        v0 = __fadd_rn(v0, __fmul_rn(__fsub_rn(xv.x, v0), 0.5f));
        v1 = __fadd_rn(v1, __fmul_rn(__fsub_rn(xv.y, v1), 0.5f));
        v2 = __fadd_rn(v2, __fmul_rn(__fsub_rn(xv.z, v2), 0.5f));
        v3 = __fadd_rn(v3, __fmul_rn(__fsub_rn(xv.w, v3), 0.5f));
        float s0 = (__fsub_rn(v0, 1.0f) >= 0.f) ? 1.f : 0.f;
        float s1 = (__fsub_rn(v1, 1.0f) >= 0.f) ? 1.f : 0.f;
        float s2 = (__fsub_rn(v2, 1.0f) >= 0.f) ? 1.f : 0.f;
        float s3 = (__fsub_rn(v3, 1.0f) >= 0.f) ? 1.f : 0.f;
        v0 = __fmul_rn(v0, 1.f - s0); v1 = __fmul_rn(v1, 1.f - s1);
        v2 = __fmul_rn(v2, 1.f - s2); v3 = __fmul_rn(v3, 1.f - s3);
        float4* op = (float4*)Out + ((size_t)(t * 32 + b0 + bl) * B4 + r);
        float4 o = *op;
        o.x = __fadd_rn(o.x, s0); o.y = __fadd_rn(o.y, s1);
        o.z = __fadd_rn(o.z, s2); o.w = __fadd_rn(o.w, s3);
        *op = o;
    }
}

// ---------------- pack 32 head-channels of binary spikes into uint32 ----------------
__global__ __launch_bounds__(256) void pack_kernel(const float* __restrict__ S,
                                                   uint32_t* __restrict__ Bits)
{
    int idx = blockIdx.x * 256 + threadIdx.x;
    if (idx >= 4 * 32 * 12 * 196) return;
    int n = idx % 196;
    int rest = idx / 196;
    int h = rest % 12;
    int tb = rest / 12;
    const float* sp = S + ((size_t)tb * 384 + h * 32) * 196 + n;
    uint32_t bits = 0;
    #pragma unroll
    for (int d = 0; d < 32; ++d)
        bits |= (sp[(size_t)d * 196] > 0.5f) ? (1u << d) : 0u;
    Bits[idx] = bits;
}

// ---------------- attention: attn = popc(q&k), policy mask, o = attn*v*0.25 ----------------
__global__ __launch_bounds__(256) void attn_kernel(
    const uint32_t* __restrict__ Qb, const uint32_t* __restrict__ Kb,
    const float* __restrict__ V, const float* __restrict__ P, float* __restrict__ O)
{
    __shared__ uint32_t Qbs[196], Kbs[196];
    __shared__ float Ps[196];
    __shared__ float Vs[32][204];
    __shared__ float Ss[32][204];
    __shared__ float Os[32][36];
    const int tid = threadIdx.x;
    const int bid = blockIdx.x;
    const int tb = bid / 12, h = bid - tb * 12;
    const size_t vbase = ((size_t)tb * 384 + h * 32) * 196;
    const size_t qbase = ((size_t)tb * 12 + h) * 196;
    for (int i = tid; i < 196; i += 256) {
        Qbs[i] = Qb[qbase + i];
        Kbs[i] = Kb[qbase + i];
        Ps[i]  = P[(size_t)tb * 196 + i];
    }
    for (int i = tid; i < 32 * 49; i += 256) {
        int d = i / 49, m4 = i - d * 49;
        *(float4*)&Vs[d][m4 * 4] = *(const float4*)(V + vbase + (size_t)d * 196 + m4 * 4);
    }
    __syncthreads();
    for (int n0 = 0; n0 < 196; n0 += 32) {
        const int rows = min(32, 196 - n0);
        for (int idx = tid; idx < rows * 196; idx += 256) {
            int ns = idx / 196, m = idx - ns * 196;
            int n = n0 + ns;
            float s = (float)__popc(Qbs[n] & Kbs[m]);
            float p = Ps[m];
            float e = (m == n) ? 1.f : 0.f;
            Ss[ns][m] = s * (p + (1.f - p) * e);
        }
        __syncthreads();
        {
            const int tn = tid & 15, td = tid >> 4;
            float a00 = 0, a01 = 0, a10 = 0, a11 = 0;
            #pragma unroll 7
            for (int m4 = 0; m4 < 49; ++m4) {
                float4 s0 = *(const float4*)&Ss[tn][m4 * 4];
                float4 s1 = *(const float4*)&Ss[tn + 16][m4 * 4];
                float4 u0 = *(const float4*)&Vs[td][m4 * 4];
                float4 u1 = *(const float4*)&Vs[td + 16][m4 * 4];
                a00 += s0.x * u0.x + s0.y * u0.y + s0.z * u0.z + s0.w * u0.w;
                a01 += s0.x * u1.x + s0.y * u1.y + s0.z * u1.z + s0.w * u1.w;
                a10 += s1.x * u0.x + s1.y * u0.y + s1.z * u0.z + s1.w * u0.w;
                a11 += s1.x * u1.x + s1.y * u1.y + s1.z * u1.z + s1.w * u1.w;
            }
            Os[td     ][tn     ] = a00 * 0.25f;
            Os[td + 16][tn     ] = a01 * 0.25f;
            Os[td     ][tn + 16] = a10 * 0.25f;
            Os[td + 16][tn + 16] = a11 * 0.25f;
        }
        __syncthreads();
        {
            const int d = tid >> 3, c4 = tid & 7;
            if (c4 * 4 < rows)
                *(float4*)(O + vbase + (size_t)d * 196 + n0 + c4 * 4) =
                    *(const float4*)&Os[d][c4 * 4];
        }
        __syncthreads();
    }
}

// ---------------- elementwise residual add: Out = A + B ----------------
__global__ __launch_bounds__(256) void add_kernel(const float* __restrict__ A,
    const float* __restrict__ B, float* __restrict__ Out, int n4)
{
    int idx = blockIdx.x * 256 + threadIdx.x;
    if (idx >= n4) return;
    float4 a = ((const float4*)A)[idx];
    float4 b = ((const float4*)B)[idx];
    float4 o;
    o.x = __fadd_rn(a.x, b.x); o.y = __fadd_rn(a.y, b.y);
    o.z = __fadd_rn(a.z, b.z); o.w = __fadd_rn(a.w, b.w);
    ((float4*)Out)[idx] = o;
}

extern "C" void kernel_launch(void* const* d_in, const int* in_sizes, int n_in,
                              void* d_out, int out_size, void* d_ws, size_t ws_size,
                              hipStream_t stream) {
    const float* x   = (const float*)d_in[0];
    const float* pol = (const float*)d_in[1];
    const float* wq = (const float*)d_in[2];
    const float* qg = (const float*)d_in[3];
    const float* qb = (const float*)d_in[4];
    const float* qm = (const float*)d_in[5];
    const float* qv = (const float*)d_in[6];
    const float* wk = (const float*)d_in[7];
    const float* kg = (const float*)d_in[8];
    const float* kb = (const float*)d_in[9];
    const float* km = (const float*)d_in[10];
    const float* kvv= (const float*)d_in[11];
    const float* wv = (const float*)d_in[12];
    const float* vg = (const float*)d_in[13];
    const float* vb = (const float*)d_in[14];
    const float* vm = (const float*)d_in[15];
    const float* vvv= (const float*)d_in[16];
    const float* wp = (const float*)d_in[17];
    const float* bp = (const float*)d_in[18];
    const float* pg = (const float*)d_in[19];
    const float* pb = (const float*)d_in[20];
    const float* pm = (const float*)d_in[21];
    const float* pv = (const float*)d_in[22];
    const float* w1 = (const float*)d_in[23];
    const float* b1 = (const float*)d_in[24];
    const float* g1 = (const float*)d_in[25];
    const float* be1= (const float*)d_in[26];
    const float* m1 = (const float*)d_in[27];
    const float* v1 = (const float*)d_in[28];
    const float* w2 = (const float*)d_in[29];
    const float* b2 = (const float*)d_in[30];
    const float* g2 = (const float*)d_in[31];
    const float* be2= (const float*)d_in[32];
    const float* m2 = (const float*)d_in[33];
    const float* v2 = (const float*)d_in[34];

    // workspace (floats), total 48.2 MiB:
    //   bufA 9,633,792 | bufD 2,408,448 | bits 602,112 u32
    float* bufA = (float*)d_ws;
    float* bufD = bufA + 9633792;
    uint32_t* Qbits = (uint32_t*)(bufD + 2408448);
    uint32_t* Kbits = Qbits + 301056;
    float* out = (float*)d_out;

    // q branch: conv+bn, LIF, pack bits; bufA reused for k, then v
    convbn_kernel<384, false, false><<<dim3(128, 6), 512, 0, stream>>>(x, wq, nullptr, qg, qb, qm, qv, bufA, 384, 32, 0, 0, 0);
    lif_kernel<<<2352, 256, 0, stream>>>(bufA, 602112, 1.0f);
    pack_kernel<<<1176, 256, 0, stream>>>(bufA, Qbits);
    convbn_kernel<384, false, false><<<dim3(128, 6), 512, 0, stream>>>(x, wk, nullptr, kg, kb, km, kvv, bufA, 384, 32, 0, 0, 0);
    lif_kernel<<<2352, 256, 0, stream>>>(bufA, 602112, 1.0f);
    pack_kernel<<<1176, 256, 0, stream>>>(bufA, Kbits);
    convbn_kernel<384, false, false><<<dim3(128, 6), 512, 0, stream>>>(x, wv, nullptr, vg, vb, vm, vvv, bufA, 384, 32, 0, 0, 0);
    lif_kernel<<<2352, 256, 0, stream>>>(bufA, 602112, 1.0f);

    // attention (exact popcount) -> d_out, then attn LIF (thr=0.5) in place
    attn_kernel<<<1536, 256, 0, stream>>>(Qbits, Kbits, bufA, pol, out);
    lif_kernel<<<2352, 256, 0, stream>>>(out, 602112, 0.5f);

    // projection conv+bn+LIF (binary input -> fma exact); residual 1: out = x + proj
    convbn_kernel<384, true, false><<<dim3(128, 6), 512, 0, stream>>>(out, wp, bp, pg, pb, pm, pv, bufA, 384, 32, 0, 0, 0);
    lif_kernel<<<2352, 256, 0, stream>>>(bufA, 602112, 1.0f);
    add_kernel<<<9408, 256, 0, stream>>>(x, bufA, out, 2408448);   // out = x1

    // MLP chunked over b in groups of 8 (t recurrence preserved):
    // fc1 -> bufA (chunk-local); LIF; fc2 -> bufD; lif_add spikes into out.
    for (int c = 0; c < 4; ++c) {
        convbn_kernel<384, false, false><<<dim3(32, 24), 512, 0, stream>>>(out, w1, b1, g1, be1, m1, v1, bufA, 1536, 8, c * 8, 0, 1);
        lif_kernel<<<2352, 256, 0, stream>>>(bufA, 602112, 1.0f);
        convbn_kernel<1536, true, false><<<dim3(32, 6), 512, 0, stream>>>(bufA, w2, b2, g2, be2, m2, v2, bufD, 384, 8, c * 8, 1, 1);
        lif_add_kernel<<<588, 256, 0, stream>>>(bufD, out, c * 8);
    }
}

// Round 8
// 2411.342 us; speedup vs baseline: 1.4301x; 1.1007x over previous
//
#include <hip/hip_runtime.h>
#include <cstdint>
#include <cstddef>

#define N_POS 196

typedef __attribute__((ext_vector_type(4))) float f32x4;

// async global->LDS DMA, 16B per lane; lds dest must be wave-uniform base (+lane*16)
__device__ __forceinline__ void async_copy16(const float* g, float* l) {
    __builtin_amdgcn_global_load_lds(
        (const __attribute__((address_space(1))) uint32_t*)g,
        (__attribute__((address_space(3))) uint32_t*)l,
        16, 0, 0);
}

// ---------------- 1x1 conv (channel matmul) + folded BatchNorm ----------------
// X: (ntb, CIN, 196)  W: (Cout, CIN) row-major  Y: (ntb, Cout, 196)
// Block: 256 thr (4 waves), one tb, 64 outputs. Thread (o=tid&31, grp=tid>>5):
// 8 outs (grp*8..+7) x 8 pos (quadA=4o..4o+3 always valid; quadB=128+4o..+3,
// valid iff o<=16; o>16 reads in-bounds garbage into dead accumulators).
// X LDS reads: 2x ds_read_b128 lane-stride-16 (conflict-free). W: 2x b128 bcast.
// K pipelined in 16-row chunks, double-buffered global_load_lds DMA.
// Math: f32x4 (v_pk_*), per-element IEEE == scalar, ascending-k sequential per
// accumulator — bitwise-matches np.einsum (absmax 0.0 proven r4-r7).
// USE_FMA=false: pk_mul+pk_add (continuous inputs). USE_FMA=true: pk_fma —
// bitwise identical for binary {0,1} inputs. ACCUM: Y += result.
template<int CIN, bool USE_FMA, bool ACCUM>
__global__ __launch_bounds__(256, 4) void convbn_kernel(
    const float* __restrict__ X, const float* __restrict__ W,
    const float* __restrict__ Bi, const float* __restrict__ Ga,
    const float* __restrict__ Be, const float* __restrict__ Mu,
    const float* __restrict__ Va, float* __restrict__ Y, int Cout,
    int nb, int b0, int xlocal, int ylocal)
{
#pragma clang fp contract(off)
    constexpr int NCH = CIN / 16;
    // Xs[2][16*196] floats | Ws[2][16*64] floats ; quadB tail reads spill into
    // the Ws region (in-bounds garbage, dead lanes only).
    __shared__ float lds[2 * 3136 + 2 * 1024];
    float* Xs = lds;
    float* Ws = lds + 6272;
    const int tid = threadIdx.x;
    const int l   = blockIdx.x;
    const int t   = l / nb;
    const int bl  = l - t * nb;
    const int tbg = t * 32 + b0 + bl;
    const int xtb = xlocal ? l : tbg;
    const int ytb = ylocal ? l : tbg;
    const int o0  = blockIdx.y * 64;
    const int o   = tid & 31;                  // position-quad index
    const int grp = tid >> 5;                  // out-group (8 outs)
    const float* Xtb = X + (size_t)xtb * CIN * N_POS;
    const float* Wp  = W + (size_t)o0 * CIN;

    f32x4 accA[8], accB[8];
    #pragma unroll
    for (int i = 0; i < 8; ++i) { accA[i] = (f32x4)0.f; accB[i] = (f32x4)0.f; }

    // stage chunk kc..kc+15: W->VGPR first, X DMA (stays in flight), W ds_writes
    auto stage = [&](int buf, int kc) {
        const int oo = tid >> 2, k4 = tid & 3;
        float4 wv4 = *(const float4*)(Wp + (size_t)oo * CIN + kc + k4 * 4);
        #pragma unroll
        for (int j = 0; j < 4; ++j) {
            int i = tid + j * 256;
            if (i < 784)
                async_copy16(Xtb + (size_t)(kc + i / 49) * N_POS + (i % 49) * 4,
                             &Xs[buf * 3136 + (i & ~63) * 4]);
        }
        Ws[buf * 1024 + (k4 * 4 + 0) * 64 + oo] = wv4.x;
        Ws[buf * 1024 + (k4 * 4 + 1) * 64 + oo] = wv4.y;
        Ws[buf * 1024 + (k4 * 4 + 2) * 64 + oo] = wv4.z;
        Ws[buf * 1024 + (k4 * 4 + 3) * 64 + oo] = wv4.w;
    };

    stage(0, 0);
    __syncthreads();                 // drains prologue DMA
    int buf = 0;
    for (int ch = 0; ch < NCH; ++ch) {
        if (ch + 1 < NCH) stage(buf ^ 1, (ch + 1) * 16);
        const float* Xb = Xs + buf * 3136 + o * 4;
        const float* Wb = Ws + buf * 1024 + grp * 8;
        #pragma unroll
        for (int kk = 0; kk < 16; ++kk) {
            f32x4 xA = *(const f32x4*)(Xb + kk * 196);          // b128, stride-16
            f32x4 xB = *(const f32x4*)(Xb + kk * 196 + 128);    // b128, stride-16
            float4 wA = *(const float4*)(Wb + kk * 64);         // b128 bcast
            float4 wB = *(const float4*)(Wb + kk * 64 + 4);
            float w8[8] = { wA.x, wA.y, wA.z, wA.w, wB.x, wB.y, wB.z, wB.w };
            #pragma unroll
            for (int i = 0; i < 8; ++i) {
                f32x4 wd = { w8[i], w8[i], w8[i], w8[i] };
                if (USE_FMA) {
                    accA[i] = __builtin_elementwise_fma(wd, xA, accA[i]);
                    accB[i] = __builtin_elementwise_fma(wd, xB, accB[i]);
                } else {
                    accA[i] = accA[i] + wd * xA;   // v_pk_mul + v_pk_add
                    accB[i] = accB[i] + wd * xB;
                }
            }
        }
        __syncthreads();             // next chunk DMA complete; buf reusable
        buf ^= 1;
    }

    #pragma unroll
    for (int i = 0; i < 8; ++i) {
        int oo = o0 + grp * 8 + i;
        // reference op order: inv = g*rsqrt(var+eps); y = conv (+ bias);
        // r = y*inv + (beta - m*inv)
        float sc = __fmul_rn(Ga[oo], 1.0f / sqrtf(__fadd_rn(Va[oo], 1e-5f)));
        float sh = __fsub_rn(Be[oo], __fmul_rn(Mu[oo], sc));
        float bi = Bi ? Bi[oo] : 0.f;
        float* yp = Y + ((size_t)ytb * Cout + oo) * N_POS;
        {   // quadA: pos 4o..4o+3 (always valid)
            float a[4] = { accA[i].x, accA[i].y, accA[i].z, accA[i].w };
            float4 r;
            float* rp = &r.x;
            #pragma unroll
            for (int j = 0; j < 4; ++j) {
                float y = Bi ? __fadd_rn(a[j], bi) : a[j];
                rp[j] = __fadd_rn(__fmul_rn(y, sc), sh);
            }
            float* dst = yp + o * 4;
            if (ACCUM) {
                float4 y0 = *(const float4*)dst;
                r.x = __fadd_rn(y0.x, r.x); r.y = __fadd_rn(y0.y, r.y);
                r.z = __fadd_rn(y0.z, r.z); r.w = __fadd_rn(y0.w, r.w);
            }
            *(float4*)dst = r;
        }
        if (o <= 16) {  // quadB: pos 128+4o..131+4o (o=16 -> 192..195)
            float a[4] = { accB[i].x, accB[i].y, accB[i].z, accB[i].w };
            float4 r;
            float* rp = &r.x;
            #pragma unroll
            for (int j = 0; j < 4; ++j) {
                float y = Bi ? __fadd_rn(a[j], bi) : a[j];
                rp[j] = __fadd_rn(__fmul_rn(y, sc), sh);
            }
            float* dst = yp + 128 + o * 4;
            if (ACCUM) {
                float4 y0 = *(const float4*)dst;
                r.x = __fadd_rn(y0.x, r.x); r.y = __fadd_rn(y0.y, r.y);
                r.z = __fadd_rn(y0.z, r.z); r.w = __fadd_rn(y0.w, r.w);
            }
            *(float4*)dst = r;
        }
    }
}

// ---------------- multi-step LIF (in place, scan over T=4) ----------------
__global__ __launch_bounds__(256) void lif_kernel(float* __restrict__ Y, int plane4, float thr)
{
    int idx = blockIdx.x * 256 + threadIdx.x;
    if (idx >= plane4) return;
    float4* Yp = (float4*)Y;
    float v0 = 0.f, v1 = 0.f, v2 = 0.f, v3 = 0.f;
    #pragma unroll
    for (int t = 0; t < 4; ++t) {
        float4 xv = Yp[(size_t)t * plane4 + idx];
        v0 = __fadd_rn(v0, __fmul_rn(__fsub_rn(xv.x, v0), 0.5f));
        v1 = __fadd_rn(v1, __fmul_rn(__fsub_rn(xv.y, v1), 0.5f));
        v2 = __fadd_rn(v2, __fmul_rn(__fsub_rn(xv.z, v2), 0.5f));
        v3 = __fadd_rn(v3, __fmul_rn(__fsub_rn(xv.w, v3), 0.5f));
        float s0 = (__fsub_rn(v0, thr) >= 0.f) ? 1.f : 0.f;
        float s1 = (__fsub_rn(v1, thr) >= 0.f) ? 1.f : 0.f;
        float s2 = (__fsub_rn(v2, thr) >= 0.f) ? 1.f : 0.f;
        float s3 = (__fsub_rn(v3, thr) >= 0.f) ? 1.f : 0.f;
        v0 = __fmul_rn(v0, 1.f - s0); v1 = __fmul_rn(v1, 1.f - s1);
        v2 = __fmul_rn(v2, 1.f - s2); v3 = __fmul_rn(v3, 1.f - s3);
        xv.x = s0; xv.y = s1; xv.z = s2; xv.w = s3;
        Yp[(size_t)t * plane4 + idx] = xv;
    }
}

// ---------------- LIF scan + accumulate spikes into global output ----------------
__global__ __launch_bounds__(256) void lif_add_kernel(
    const float* __restrict__ Yin, float* __restrict__ Out, int b0)
{
    const int PL4 = 8 * 384 * 49;
    const int B4  = 384 * 49;
    int idx = blockIdx.x * 256 + threadIdx.x;
    if (idx >= PL4) return;
    int bl = idx / B4, r = idx - bl * B4;
    const float4* Yp = (const float4*)Yin;
    float v0 = 0.f, v1 = 0.f, v2 = 0.f, v3 = 0.f;
    #pragma unroll
    for (int t = 0; t < 4; ++t) {
        float4 xv = Yp[(size_t)t * PL4 + idx];
        v0 = __fadd_rn(v0, __fmul_rn(__fsub_rn(xv.x, v0), 0.5f));
        v1 = __fadd_rn(v1, __fmul_rn(__fsub_rn(xv.y, v1), 0.5f));
        v2 = __fadd_rn(v2, __fmul_rn(__fsub_rn(xv.z, v2), 0.5f));
        v3 = __fadd_rn(v3, __fmul_rn(__fsub_rn(xv.w, v3), 0.5f));
        float s0 = (__fsub_rn(v0, 1.0f) >= 0.f) ? 1.f : 0.f;
        float s1 = (__fsub_rn(v1, 1.0f) >= 0.f) ? 1.f : 0.f;
        float s2 = (__fsub_rn(v2, 1.0f) >= 0.f) ? 1.f : 0.f;
        float s3 = (__fsub_rn(v3, 1.0f) >= 0.f) ? 1.f : 0.f;
        v0 = __fmul_rn(v0, 1.f - s0); v1 = __fmul_rn(v1, 1.f - s1);
        v2 = __fmul_rn(v2, 1.f - s2); v3 = __fmul_rn(v3, 1.f - s3);
        float4* op = (float4*)Out + ((size_t)(t * 32 + b0 + bl) * B4 + r);
        float4 o = *op;
        o.x = __fadd_rn(o.x, s0); o.y = __fadd_rn(o.y, s1);
        o.z = __fadd_rn(o.z, s2); o.w = __fadd_rn(o.w, s3);
        *op = o;
    }
}

// ---------------- pack 32 head-channels of binary spikes into uint32 ----------------
__global__ __launch_bounds__(256) void pack_kernel(const float* __restrict__ S,
                                                   uint32_t* __restrict__ Bits)
{
    int idx = blockIdx.x * 256 + threadIdx.x;
    if (idx >= 4 * 32 * 12 * 196) return;
    int n = idx % 196;
    int rest = idx / 196;
    int h = rest % 12;
    int tb = rest / 12;
    const float* sp = S + ((size_t)tb * 384 + h * 32) * 196 + n;
    uint32_t bits = 0;
    #pragma unroll
    for (int d = 0; d < 32; ++d)
        bits |= (sp[(size_t)d * 196] > 0.5f) ? (1u << d) : 0u;
    Bits[idx] = bits;
}

// ---------------- attention: attn = popc(q&k), policy mask, o = attn*v*0.25 ----------------
__global__ __launch_bounds__(256) void attn_kernel(
    const uint32_t* __restrict__ Qb, const uint32_t* __restrict__ Kb,
    const float* __restrict__ V, const float* __restrict__ P, float* __restrict__ O)
{
    __shared__ uint32_t Qbs[196], Kbs[196];
    __shared__ float Ps[196];
    __shared__ float Vs[32][204];
    __shared__ float Ss[32][204];
    __shared__ float Os[32][36];
    const int tid = threadIdx.x;
    const int bid = blockIdx.x;
    const int tb = bid / 12, h = bid - tb * 12;
    const size_t vbase = ((size_t)tb * 384 + h * 32) * 196;
    const size_t qbase = ((size_t)tb * 12 + h) * 196;
    for (int i = tid; i < 196; i += 256) {
        Qbs[i] = Qb[qbase + i];
        Kbs[i] = Kb[qbase + i];
        Ps[i]  = P[(size_t)tb * 196 + i];
    }
    for (int i = tid; i < 32 * 49; i += 256) {
        int d = i / 49, m4 = i - d * 49;
        *(float4*)&Vs[d][m4 * 4] = *(const float4*)(V + vbase + (size_t)d * 196 + m4 * 4);
    }
    __syncthreads();
    for (int n0 = 0; n0 < 196; n0 += 32) {
        const int rows = min(32, 196 - n0);
        for (int idx = tid; idx < rows * 196; idx += 256) {
            int ns = idx / 196, m = idx - ns * 196;
            int n = n0 + ns;
            float s = (float)__popc(Qbs[n] & Kbs[m]);
            float p = Ps[m];
            float e = (m == n) ? 1.f : 0.f;
            Ss[ns][m] = s * (p + (1.f - p) * e);
        }
        __syncthreads();
        {
            const int tn = tid & 15, td = tid >> 4;
            float a00 = 0, a01 = 0, a10 = 0, a11 = 0;
            #pragma unroll 7
            for (int m4 = 0; m4 < 49; ++m4) {
                float4 s0 = *(const float4*)&Ss[tn][m4 * 4];
                float4 s1 = *(const float4*)&Ss[tn + 16][m4 * 4];
                float4 u0 = *(const float4*)&Vs[td][m4 * 4];
                float4 u1 = *(const float4*)&Vs[td + 16][m4 * 4];
                a00 += s0.x * u0.x + s0.y * u0.y + s0.z * u0.z + s0.w * u0.w;
                a01 += s0.x * u1.x + s0.y * u1.y + s0.z * u1.z + s0.w * u1.w;
                a10 += s1.x * u0.x + s1.y * u0.y + s1.z * u0.z + s1.w * u0.w;
                a11 += s1.x * u1.x + s1.y * u1.y + s1.z * u1.z + s1.w * u1.w;
            }
            Os[td     ][tn     ] = a00 * 0.25f;
            Os[td + 16][tn     ] = a01 * 0.25f;
            Os[td     ][tn + 16] = a10 * 0.25f;
            Os[td + 16][tn + 16] = a11 * 0.25f;
        }
        __syncthreads();
        {
            const int d = tid >> 3, c4 = tid & 7;
            if (c4 * 4 < rows)
                *(float4*)(O + vbase + (size_t)d * 196 + n0 + c4 * 4) =
                    *(const float4*)&Os[d][c4 * 4];
        }
        __syncthreads();
    }
}

// ---------------- elementwise residual add: Out = A + B ----------------
__global__ __launch_bounds__(256) void add_kernel(const float* __restrict__ A,
    const float* __restrict__ B, float* __restrict__ Out, int n4)
{
    int idx = blockIdx.x * 256 + threadIdx.x;
    if (idx >= n4) return;
    float4 a = ((const float4*)A)[idx];
    float4 b = ((const float4*)B)[idx];
    float4 o;
    o.x = __fadd_rn(a.x, b.x); o.y = __fadd_rn(a.y, b.y);
    o.z = __fadd_rn(a.z, b.z); o.w = __fadd_rn(a.w, b.w);
    ((float4*)Out)[idx] = o;
}

extern "C" void kernel_launch(void* const* d_in, const int* in_sizes, int n_in,
                              void* d_out, int out_size, void* d_ws, size_t ws_size,
                              hipStream_t stream) {
    const float* x   = (const float*)d_in[0];
    const float* pol = (const float*)d_in[1];
    const float* wq = (const float*)d_in[2];
    const float* qg = (const float*)d_in[3];
    const float* qb = (const float*)d_in[4];
    const float* qm = (const float*)d_in[5];
    const float* qv = (const float*)d_in[6];
    const float* wk = (const float*)d_in[7];
    const float* kg = (const float*)d_in[8];
    const float* kb = (const float*)d_in[9];
    const float* km = (const float*)d_in[10];
    const float* kvv= (const float*)d_in[11];
    const float* wv = (const float*)d_in[12];
    const float* vg = (const float*)d_in[13];
    const float* vb = (const float*)d_in[14];
    const float* vm = (const float*)d_in[15];
    const float* vvv= (const float*)d_in[16];
    const float* wp = (const float*)d_in[17];
    const float* bp = (const float*)d_in[18];
    const float* pg = (const float*)d_in[19];
    const float* pb = (const float*)d_in[20];
    const float* pm = (const float*)d_in[21];
    const float* pv = (const float*)d_in[22];
    const float* w1 = (const float*)d_in[23];
    const float* b1 = (const float*)d_in[24];
    const float* g1 = (const float*)d_in[25];
    const float* be1= (const float*)d_in[26];
    const float* m1 = (const float*)d_in[27];
    const float* v1 = (const float*)d_in[28];
    const float* w2 = (const float*)d_in[29];
    const float* b2 = (const float*)d_in[30];
    const float* g2 = (const float*)d_in[31];
    const float* be2= (const float*)d_in[32];
    const float* m2 = (const float*)d_in[33];
    const float* v2 = (const float*)d_in[34];

    // workspace (floats), total 48.2 MiB:
    //   bufA 9,633,792 | bufD 2,408,448 | bits 602,112 u32
    float* bufA = (float*)d_ws;
    float* bufD = bufA + 9633792;
    uint32_t* Qbits = (uint32_t*)(bufD + 2408448);
    uint32_t* Kbits = Qbits + 301056;
    float* out = (float*)d_out;

    // q branch: conv+bn, LIF, pack bits; bufA reused for k, then v
    convbn_kernel<384, false, false><<<dim3(128, 6), 256, 0, stream>>>(x, wq, nullptr, qg, qb, qm, qv, bufA, 384, 32, 0, 0, 0);
    lif_kernel<<<2352, 256, 0, stream>>>(bufA, 602112, 1.0f);
    pack_kernel<<<1176, 256, 0, stream>>>(bufA, Qbits);
    convbn_kernel<384, false, false><<<dim3(128, 6), 256, 0, stream>>>(x, wk, nullptr, kg, kb, km, kvv, bufA, 384, 32, 0, 0, 0);
    lif_kernel<<<2352, 256, 0, stream>>>(bufA, 602112, 1.0f);
    pack_kernel<<<1176, 256, 0, stream>>>(bufA, Kbits);
    convbn_kernel<384, false, false><<<dim3(128, 6), 256, 0, stream>>>(x, wv, nullptr, vg, vb, vm, vvv, bufA, 384, 32, 0, 0, 0);
    lif_kernel<<<2352, 256, 0, stream>>>(bufA, 602112, 1.0f);

    // attention (exact popcount) -> d_out, then attn LIF (thr=0.5) in place
    attn_kernel<<<1536, 256, 0, stream>>>(Qbits, Kbits, bufA, pol, out);
    lif_kernel<<<2352, 256, 0, stream>>>(out, 602112, 0.5f);

    // projection conv+bn+LIF (binary input -> fma exact); residual 1: out = x + proj
    convbn_kernel<384, true, false><<<dim3(128, 6), 256, 0, stream>>>(out, wp, bp, pg, pb, pm, pv, bufA, 384, 32, 0, 0, 0);
    lif_kernel<<<2352, 256, 0, stream>>>(bufA, 602112, 1.0f);
    add_kernel<<<9408, 256, 0, stream>>>(x, bufA, out, 2408448);   // out = x1

    // MLP chunked over b in groups of 8 (t recurrence preserved):
    // fc1 -> bufA (chunk-local); LIF; fc2 -> bufD; lif_add spikes into out.
    for (int c = 0; c < 4; ++c) {
        convbn_kernel<384, false, false><<<dim3(32, 24), 256, 0, stream>>>(out, w1, b1, g1, be1, m1, v1, bufA, 1536, 8, c * 8, 0, 1);
        lif_kernel<<<2352, 256, 0, stream>>>(bufA, 602112, 1.0f);
        convbn_kernel<1536, true, false><<<dim3(32, 6), 256, 0, stream>>>(bufA, w2, b2, g2, be2, m2, v2, bufD, 384, 8, c * 8, 1, 1);
        lif_add_kernel<<<588, 256, 0, stream>>>(bufD, out, c * 8);
    }
}